// Round 15
// baseline (120.064 us; speedup 1.0000x reference)
//
#include <hip/hip_runtime.h>
#include <hip/hip_fp16.h>

#define TPB 256
#define NEG_SLOPE 0.2f
#define B1 256          // blocks for hist/place passes
#define DPB 512         // dsts per bucket
#define MAXNB 128       // max buckets

// ---------- helpers ----------
__device__ __forceinline__ int getIdx(const void* p, int is32, long long i) {
  return is32 ? ((const int*)p)[i] : (int)((const long long*)p)[i];
}

// ---------- device bodies ----------

// layer 1 GEMM body: one block handles 4 nodes (proven R11/R13 form)
__device__ __forceinline__ void gemm1_body(
    int gb, const float* __restrict__ x, const float* __restrict__ W1,
    const float* __restrict__ aS, const float* __restrict__ aD,
    __half* __restrict__ h1, float* __restrict__ asrc, float* __restrict__ adst,
    int N, float* Wl, float (*xr)[64]) {
  int t = threadIdx.x;
  for (int i = t; i < 64 * 64; i += TPB) Wl[i] = W1[i];
  int w = t >> 6, lane = t & 63;
  int node = gb * 4 + w;
  if (node < N) xr[w][lane] = x[(size_t)node * 64 + lane];
  __syncthreads();
  if (node >= N) return;
  float acc = 0.f;
#pragma unroll
  for (int k = 0; k < 64; ++k) acc = fmaf(xr[w][k], Wl[k * 64 + lane], acc);
  h1[(size_t)node * 64 + lane] = __float2half(acc);
  float vs = acc * aS[lane];
  float vd = acc * aD[lane];
#pragma unroll
  for (int m = 16; m >= 1; m >>= 1) {
    vs += __shfl_xor(vs, m, 64);
    vd += __shfl_xor(vd, m, 64);
  }
  if ((lane & 31) == 0) {
    asrc[node * 2 + (lane >> 5)] = vs;
    adst[node * 2 + (lane >> 5)] = vd;
  }
}

// ---------- fat kernel 1: CSR histogram (blocks 0..B1) + gemm1 first half ----------
__global__ __launch_bounds__(TPB) void k_fat1(
    const void* __restrict__ ei, int E, int Etot,
    int* __restrict__ histA, int NB, int CH,
    const float* __restrict__ x, const float* __restrict__ W1,
    const float* __restrict__ aS, const float* __restrict__ aD,
    __half* __restrict__ h1, float* __restrict__ asrc, float* __restrict__ adst,
    int N) {
  __shared__ float Wl[64 * 64];
  __shared__ float xr[4][64];
  __shared__ int lh[MAXNB];
  __shared__ int sflag;
  if (blockIdx.x >= B1) {
    gemm1_body((int)blockIdx.x - B1, x, W1, aS, aD, h1, asrc, adst, N, Wl, xr);
    return;
  }
  int b = blockIdx.x, tid = threadIdx.x;
  for (int i = tid; i < NB; i += TPB) lh[i] = 0;
  if (tid < 64) {  // wave 0: sniff int32 vs int64 storage (ids < 2^31)
    const unsigned long long* p = (const unsigned long long*)ei;
    unsigned long long m = __ballot(tid < E && p[tid] > 0xFFFFFFFFULL);
    if (tid == 0) sflag = (m != 0ULL) ? 1 : 0;
  }
  __syncthreads();
  int f = sflag;
  int beg = b * CH, end = min(beg + CH, Etot);
  for (int e = beg + tid; e < end; e += TPB) {
    int d = (e < E) ? getIdx(ei, f, (long long)E + e) : e - E;
    atomicAdd(&lh[d / DPB], 1);
  }
  __syncthreads();
  for (int i = tid; i < NB; i += TPB) histA[b * NB + i] = lh[i];  // [block][bucket]
}

// ---------- fat kernel 2: CSR place (scan inlined) + gemm1 second half ----------
__global__ __launch_bounds__(TPB) void k_fat2(
    const void* __restrict__ ei, int E, int Etot,
    const int* __restrict__ histA, int* __restrict__ bucketBase,
    int2* __restrict__ pairs, int NB, int CH,
    const float* __restrict__ x, const float* __restrict__ W1,
    const float* __restrict__ aS, const float* __restrict__ aD,
    __half* __restrict__ h1, float* __restrict__ asrc, float* __restrict__ adst,
    int N, int gOff) {
  __shared__ float Wl[64 * 64];
  __shared__ float xr[4][64];
  __shared__ int cur[MAXNB];
  __shared__ int sh[TPB];
  __shared__ int sflag;
  if (blockIdx.x >= B1) {
    gemm1_body((int)blockIdx.x - B1 + gOff, x, W1, aS, aD, h1, asrc, adst, N, Wl, xr);
    return;
  }
  int b = blockIdx.x, tid = threadIdx.x;
  int before = 0, tot = 0;
  if (tid < NB) {
    for (int bb = 0; bb < B1; ++bb) {        // coalesced: histA[bb*NB + tid]
      int v = histA[bb * NB + tid];
      tot += v;
      if (bb < b) before += v;
    }
  }
  if (tid < 64) {
    const unsigned long long* p = (const unsigned long long*)ei;
    unsigned long long m = __ballot(tid < E && p[tid] > 0xFFFFFFFFULL);
    if (tid == 0) sflag = (m != 0ULL) ? 1 : 0;
  }
  sh[tid] = (tid < NB) ? tot : 0;
  __syncthreads();
  for (int off = 1; off < TPB; off <<= 1) {
    int v = (tid >= off) ? sh[tid - off] : 0;
    __syncthreads();
    sh[tid] += v;
    __syncthreads();
  }
  int excl = sh[tid] - ((tid < NB) ? tot : 0);
  if (tid < NB) cur[tid] = excl + before;
  if (b == 0 && tid < NB) bucketBase[tid] = excl;
  if (b == 0 && tid == NB - 1) bucketBase[NB] = sh[tid];  // total == Etot
  int f = sflag;
  __syncthreads();
  int beg = b * CH, end = min(beg + CH, Etot);
  for (int e = beg + tid; e < end; e += TPB) {
    int s, d;
    if (e < E) {
      s = getIdx(ei, f, e);
      d = getIdx(ei, f, (long long)E + e);
    } else {
      s = d = e - E;
    }
    int pos = atomicAdd(&cur[d / DPB], 1);
    pairs[pos] = make_int2(s, d);
  }
}

// ---------- CSR stage 3: per-bucket rowptr + csr_src + INLINE layer-1 weights ----------
// as1/ad1 are complete (fat2 ran). For each placed edge also emit
// wE1[pos] = {exp(lrelu(as1.x+ad1.x)), exp(lrelu(as1.y+ad1.y))} — removing the
// dependent alpha-gather + exp from gather1f's critical path.
__global__ __launch_bounds__(DPB) void k_bucket(
    const int2* __restrict__ pairs, const int* __restrict__ bucketBase,
    const float* __restrict__ as1, const float* __restrict__ ad1,
    int* __restrict__ rowptr, int* __restrict__ csr_src,
    float* __restrict__ wE1, int N, int Etot) {
  __shared__ int cnt[DPB];
  __shared__ int sc[DPB];
  int g = blockIdx.x, tid = threadIdx.x;
  int base = g * DPB;
  int nd = N - base; if (nd > DPB) nd = DPB;
  cnt[tid] = 0;
  __syncthreads();
  int beg = bucketBase[g], end = bucketBase[g + 1];
  for (int j = beg + tid; j < end; j += DPB)
    atomicAdd(&cnt[pairs[j].y & (DPB - 1)], 1);
  __syncthreads();
  sc[tid] = cnt[tid];
  __syncthreads();
  for (int off = 1; off < DPB; off <<= 1) {
    int v = (tid >= off) ? sc[tid - off] : 0;
    __syncthreads();
    sc[tid] += v;
    __syncthreads();
  }
  int excl = beg + sc[tid] - cnt[tid];
  if (tid < nd) rowptr[base + tid] = excl;
  if (g == 0 && tid == 0) rowptr[N] = Etot;
  __syncthreads();
  cnt[tid] = excl;  // becomes cursor
  __syncthreads();
  for (int j = beg + tid; j < end; j += DPB) {
    int2 p = pairs[j];
    int pos = atomicAdd(&cnt[p.y & (DPB - 1)], 1);
    csr_src[pos] = p.x;
    float2 av = *(const float2*)(as1 + (size_t)p.x * 2);  // L2-resident 400KB table
    float2 dv = *(const float2*)(ad1 + (size_t)p.y * 2);  // 4KB hot window
    float v0 = av.x + dv.x, v1 = av.y + dv.y;
    v0 = v0 > 0.f ? v0 : NEG_SLOPE * v0;
    v1 = v1 > 0.f ? v1 : NEG_SLOPE * v1;
    *(float2*)(wE1 + (size_t)pos * 2) = make_float2(__expf(v0), __expf(v1));
  }
}

// ---------- fused layer-1 gather + layer-2 linear: half-wave per node ----------
// Phase 1 now: two INDEPENDENT coalesced loads (csr_src, wE1) — no dependent
// alpha gather, no exp. Phase 2 unchanged (2-deep unrolled h1 row gathers).
__global__ __launch_bounds__(TPB) void k_gather1f(
    const int* __restrict__ rowptr, const int* __restrict__ csr_src,
    const float* __restrict__ wE1,
    const __half* __restrict__ h1, const float* __restrict__ b1,
    const float* __restrict__ W2, const float* __restrict__ aS2,
    const float* __restrict__ aD2,
    __half* __restrict__ h2, float* __restrict__ as2, float* __restrict__ ad2, int N) {
  __shared__ float W2s[64 * 32];
  __shared__ float aS2s[32], aD2s[32];
  __shared__ int   sSid[8][32];
  __shared__ float sWp[8][64];
  __shared__ float rowBuf[8][64];
  int t = threadIdx.x;
  for (int i = t; i < 64 * 32; i += TPB) W2s[i] = W2[i];
  if (t < 32) { aS2s[t] = aS2[t]; aD2s[t] = aD2[t]; }
  __syncthreads();

  int hw = t >> 5, lane32 = t & 31;
  int node = blockIdx.x * 8 + hw;
  if (node >= N) return;

  int e4 = lane32 >> 3, c8 = lane32 & 7;  // c8 owns halfs [c8*8, c8*8+8)
  int head = c8 >> 2;                     // head of those 8 feats
  int beg = rowptr[node], end = rowptr[node + 1];
  float a0 = 0.f, a1 = 0.f, a2 = 0.f, a3 = 0.f;
  float a4 = 0.f, a5 = 0.f, a6 = 0.f, a7 = 0.f;
  float d0L = 0.f, d1L = 0.f;
  for (int chunk = beg; chunk < end; chunk += 32) {
    int m = end - chunk; if (m > 32) m = 32;
    int sid = 0; float w0 = 0.f, w1 = 0.f;   // zero-pad: wgt 0 contributes nothing
    if (lane32 < m) {                        // phase 1: 2 independent coalesced loads
      sid = csr_src[chunk + lane32];
      float2 wv = *(const float2*)(wE1 + (size_t)(chunk + lane32) * 2);
      w0 = wv.x; w1 = wv.y;
      d0L += w0; d1L += w1;
    }
    sSid[hw][lane32] = sid;                  // unconditional full staging
    *(float2*)&sWp[hw][lane32 * 2] = make_float2(w0, w1);
    // same-wave LDS handoff (lockstep, in-order LDS pipe)
    for (int j = 0; j < m; j += 8) {         // phase 2: 8 edges per iteration
      int j0 = j + e4, j1 = j0 + 4;
      int s0 = sSid[hw][j0], s1 = sSid[hw][j1];
      float q0 = sWp[hw][j0 * 2 + head], q1 = sWp[hw][j1 * 2 + head];
      float4 r0 = *(const float4*)(h1 + (size_t)s0 * 64 + c8 * 8);
      float4 r1 = *(const float4*)(h1 + (size_t)s1 * 64 + c8 * 8);
      const __half2* p0 = (const __half2*)&r0;
      const __half2* p1 = (const __half2*)&r1;
      float2 u;
      u = __half22float2(p0[0]); a0 = fmaf(q0, u.x, a0); a1 = fmaf(q0, u.y, a1);
      u = __half22float2(p0[1]); a2 = fmaf(q0, u.x, a2); a3 = fmaf(q0, u.y, a3);
      u = __half22float2(p0[2]); a4 = fmaf(q0, u.x, a4); a5 = fmaf(q0, u.y, a5);
      u = __half22float2(p0[3]); a6 = fmaf(q0, u.x, a6); a7 = fmaf(q0, u.y, a7);
      u = __half22float2(p1[0]); a0 = fmaf(q1, u.x, a0); a1 = fmaf(q1, u.y, a1);
      u = __half22float2(p1[1]); a2 = fmaf(q1, u.x, a2); a3 = fmaf(q1, u.y, a3);
      u = __half22float2(p1[2]); a4 = fmaf(q1, u.x, a4); a5 = fmaf(q1, u.y, a5);
      u = __half22float2(p1[3]); a6 = fmaf(q1, u.x, a6); a7 = fmaf(q1, u.y, a7);
    }
  }
  // combine the 4 edge-slot groups (xor 8,16 stays within the half-wave)
#pragma unroll
  for (int m2 = 8; m2 <= 16; m2 <<= 1) {
    a0 += __shfl_xor(a0, m2, 64); a1 += __shfl_xor(a1, m2, 64);
    a2 += __shfl_xor(a2, m2, 64); a3 += __shfl_xor(a3, m2, 64);
    a4 += __shfl_xor(a4, m2, 64); a5 += __shfl_xor(a5, m2, 64);
    a6 += __shfl_xor(a6, m2, 64); a7 += __shfl_xor(a7, m2, 64);
  }
#pragma unroll
  for (int m2 = 1; m2 <= 16; m2 <<= 1) {  // denominators over the half-wave
    d0L += __shfl_xor(d0L, m2, 64);
    d1L += __shfl_xor(d1L, m2, 64);
  }
  float inv = 1.f / ((head == 0 ? d0L : d1L) + 1e-16f);
  if (e4 == 0) {                          // lanes 0..7 of the half own the row
    float4 bb0 = *(const float4*)(b1 + c8 * 8);
    float4 bb1 = *(const float4*)(b1 + c8 * 8 + 4);
    float4 o0, o1;
    o0.x = fmaf(a0, inv, bb0.x); o0.y = fmaf(a1, inv, bb0.y);
    o0.z = fmaf(a2, inv, bb0.z); o0.w = fmaf(a3, inv, bb0.w);
    o1.x = fmaf(a4, inv, bb1.x); o1.y = fmaf(a5, inv, bb1.y);
    o1.z = fmaf(a6, inv, bb1.z); o1.w = fmaf(a7, inv, bb1.w);
    o0.x = o0.x > 0.f ? o0.x : 0.f; o0.y = o0.y > 0.f ? o0.y : 0.f;
    o0.z = o0.z > 0.f ? o0.z : 0.f; o0.w = o0.w > 0.f ? o0.w : 0.f;
    o1.x = o1.x > 0.f ? o1.x : 0.f; o1.y = o1.y > 0.f ? o1.y : 0.f;
    o1.z = o1.z > 0.f ? o1.z : 0.f; o1.w = o1.w > 0.f ? o1.w : 0.f;
    *(float4*)&rowBuf[hw][c8 * 8] = o0;
    *(float4*)&rowBuf[hw][c8 * 8 + 4] = o1;
  }
  // layer-2 dot: lane32 = output col; row broadcast + W2 from LDS (same-wave handoff)
  int c = lane32;
  float acc2 = 0.f;
#pragma unroll
  for (int k = 0; k < 64; ++k)
    acc2 = fmaf(rowBuf[hw][k], W2s[k * 32 + c], acc2);
  h2[(size_t)node * 32 + c] = __float2half(acc2);
  float vs = acc2 * aS2s[c];
  float vd = acc2 * aD2s[c];
#pragma unroll
  for (int m2 = 1; m2 <= 16; m2 <<= 1) {
    vs += __shfl_xor(vs, m2, 64);
    vd += __shfl_xor(vd, m2, 64);
  }
  if (lane32 == 0) {
    as2[node] = vs;
    ad2[node] = vd;
  }
}

// ---------- layer 2 gather: half-wave per node, 8 edge-slots, 2-deep unroll ----------
__global__ __launch_bounds__(TPB) void k_gather2(
    const int* __restrict__ rowptr, const int* __restrict__ csr_src,
    const float* __restrict__ as2, const float* __restrict__ ad2,
    const __half* __restrict__ h2, const float* __restrict__ b,
    float* __restrict__ out, int N) {
  __shared__ int   sS[8][32];
  __shared__ float sWv[8][32];
  int t = threadIdx.x;
  int hw = t >> 5, lane32 = t & 31;
  int wid = blockIdx.x * 8 + hw;
  if (wid >= N) return;
  int e8 = lane32 >> 2, c4 = lane32 & 3;   // c4 owns halfs [c4*8, c4*8+8)
  float ad = ad2[wid];
  int beg = rowptr[wid], end = rowptr[wid + 1];
  float a0 = 0.f, a1 = 0.f, a2 = 0.f, a3 = 0.f;
  float a4 = 0.f, a5 = 0.f, a6 = 0.f, a7 = 0.f;
  float dL = 0.f;
  for (int chunk = beg; chunk < end; chunk += 32) {
    int m = end - chunk; if (m > 32) m = 32;
    int sid = 0; float wv = 0.f;
    if (lane32 < m) {                      // phase 1
      sid = csr_src[chunk + lane32];
      float v = as2[sid] + ad;
      v = v > 0.f ? v : NEG_SLOPE * v;
      wv = __expf(v);
      dL += wv;
    }
    sS[hw][lane32] = sid;
    sWv[hw][lane32] = wv;
    for (int j = 0; j < m; j += 16) {      // phase 2: 16 edges per iteration
      int j0 = j + e8, j1 = j0 + 8;
      int s0 = sS[hw][j0], s1 = sS[hw][j1];
      float q0 = sWv[hw][j0], q1 = sWv[hw][j1];
      float4 r0 = *(const float4*)(h2 + (size_t)s0 * 32 + c4 * 8);
      float4 r1 = *(const float4*)(h2 + (size_t)s1 * 32 + c4 * 8);
      const __half2* p0 = (const __half2*)&r0;
      const __half2* p1 = (const __half2*)&r1;
      float2 u;
      u = __half22float2(p0[0]); a0 = fmaf(q0, u.x, a0); a1 = fmaf(q0, u.y, a1);
      u = __half22float2(p0[1]); a2 = fmaf(q0, u.x, a2); a3 = fmaf(q0, u.y, a3);
      u = __half22float2(p0[2]); a4 = fmaf(q0, u.x, a4); a5 = fmaf(q0, u.y, a5);
      u = __half22float2(p0[3]); a6 = fmaf(q0, u.x, a6); a7 = fmaf(q0, u.y, a7);
      u = __half22float2(p1[0]); a0 = fmaf(q1, u.x, a0); a1 = fmaf(q1, u.y, a1);
      u = __half22float2(p1[1]); a2 = fmaf(q1, u.x, a2); a3 = fmaf(q1, u.y, a3);
      u = __half22float2(p1[2]); a4 = fmaf(q1, u.x, a4); a5 = fmaf(q1, u.y, a5);
      u = __half22float2(p1[3]); a6 = fmaf(q1, u.x, a6); a7 = fmaf(q1, u.y, a7);
    }
  }
#pragma unroll
  for (int m2 = 4; m2 <= 16; m2 <<= 1) {   // combine the 8 edge-slot groups
    a0 += __shfl_xor(a0, m2, 64); a1 += __shfl_xor(a1, m2, 64);
    a2 += __shfl_xor(a2, m2, 64); a3 += __shfl_xor(a3, m2, 64);
    a4 += __shfl_xor(a4, m2, 64); a5 += __shfl_xor(a5, m2, 64);
    a6 += __shfl_xor(a6, m2, 64); a7 += __shfl_xor(a7, m2, 64);
  }
#pragma unroll
  for (int m2 = 1; m2 <= 16; m2 <<= 1) dL += __shfl_xor(dL, m2, 64);
  if (e8 == 0) {                           // lanes 0..3 of the half own the row
    float inv = 1.f / (dL + 1e-16f);
    float4 bv0 = *(const float4*)(b + c4 * 8);
    float4 bv1 = *(const float4*)(b + c4 * 8 + 4);
    float4 o0, o1;
    o0.x = fmaf(a0, inv, bv0.x); o0.y = fmaf(a1, inv, bv0.y);
    o0.z = fmaf(a2, inv, bv0.z); o0.w = fmaf(a3, inv, bv0.w);
    o1.x = fmaf(a4, inv, bv1.x); o1.y = fmaf(a5, inv, bv1.y);
    o1.z = fmaf(a6, inv, bv1.z); o1.w = fmaf(a7, inv, bv1.w);
    *(float4*)(out + (size_t)wid * 32 + c4 * 8) = o0;
    *(float4*)(out + (size_t)wid * 32 + c4 * 8 + 4) = o1;
  }
}

extern "C" void kernel_launch(void* const* d_in, const int* in_sizes, int n_in,
                              void* d_out, int out_size, void* d_ws, size_t ws_size,
                              hipStream_t stream) {
  const float* x   = (const float*)d_in[0];
  const void*  ei  = d_in[1];
  const float* W1  = (const float*)d_in[2];
  const float* aS1 = (const float*)d_in[3];
  const float* aD1 = (const float*)d_in[4];
  const float* b1  = (const float*)d_in[5];
  const float* W2  = (const float*)d_in[6];
  const float* aS2 = (const float*)d_in[7];
  const float* aD2 = (const float*)d_in[8];
  const float* b2  = (const float*)d_in[9];
  float* out = (float*)d_out;

  int N = in_sizes[0] / 64;
  int E = in_sizes[1] / 2;
  int Etot = E + N;
  int NB = (N + DPB - 1) / DPB;         // dst buckets
  int CH = (Etot + B1 - 1) / B1;        // edges per hist/place block
  int gAll = (N + 3) / 4;               // gemm1 blocks total
  int g1 = gAll / 2, g2 = gAll - g1;    // split across the two fat kernels

  float* W = (float*)d_ws;
  size_t o = 0;
  __half* h1 = (__half*)(W + o); o += (size_t)N * 32;   // N*64 halfs
  // pairs (int2, Etot) shares storage with h2 (N*32 halfs): disjoint lifetimes
  size_t regB = (size_t)(2 * (size_t)Etot > (size_t)N * 16 ? 2 * (size_t)Etot : (size_t)N * 16);
  int2* pairs = (int2*)(W + o);
  __half* h2  = (__half*)(W + o);
  o += regB;
  float* as1  = W + o; o += (size_t)N * 2;
  float* ad1  = W + o; o += (size_t)N * 2;
  float* as2  = W + o; o += (size_t)N;
  float* ad2  = W + o; o += (size_t)N;
  float* wE1  = W + o; o += (size_t)Etot * 2;   // layer-1 softmax weights (both heads)
  int* ip = (int*)(W + o);
  size_t io = 0;
  int* histA      = ip + io; io += (size_t)NB * B1;
  int* bucketBase = ip + io; io += NB + 1;
  int* rowptr     = ip + io; io += N + 1;
  int* csr_src    = ip + io; io += Etot;

  // CSR build overlapped with gemm1 (independent work rides along as extra blocks)
  k_fat1<<<B1 + g1, TPB, 0, stream>>>(ei, E, Etot, histA, NB, CH,
                                      x, W1, aS1, aD1, h1, as1, ad1, N);
  k_fat2<<<B1 + g2, TPB, 0, stream>>>(ei, E, Etot, histA, bucketBase, pairs, NB, CH,
                                      x, W1, aS1, aD1, h1, as1, ad1, N, g1);
  // bucket also emits layer-1 edge weights (as1/ad1 complete here)
  k_bucket<<<NB, DPB, 0, stream>>>(pairs, bucketBase, as1, ad1,
                                   rowptr, csr_src, wE1, N, Etot);

  // fused layer-1 gather + layer-2 linear
  k_gather1f<<<(N + 7) / 8, TPB, 0, stream>>>(rowptr, csr_src, wE1, h1, b1,
                                              W2, aS2, aD2, h2, as2, ad2, N);

  // layer 2 gather -> output
  k_gather2<<<(N + 7) / 8, TPB, 0, stream>>>(rowptr, csr_src, as2, ad2, h2, b2, out, N);
}

// Round 16
// 106.331 us; speedup vs baseline: 1.1292x; 1.1292x over previous
//
#include <hip/hip_runtime.h>
#include <hip/hip_fp16.h>

#define TPB 256
#define NEG_SLOPE 0.2f
#define B1 256          // blocks for hist/place passes
#define DPB 256         // dsts per bucket (256 -> ~196 bucket blocks, full CU coverage)
#define MAXNB 256       // max buckets

// ---------- helpers ----------
__device__ __forceinline__ int getIdx(const void* p, int is32, long long i) {
  return is32 ? ((const int*)p)[i] : (int)((const long long*)p)[i];
}

// ---------- device bodies ----------

// layer 1 GEMM body: one block handles 4 nodes (proven R11/R13 form)
__device__ __forceinline__ void gemm1_body(
    int gb, const float* __restrict__ x, const float* __restrict__ W1,
    const float* __restrict__ aS, const float* __restrict__ aD,
    __half* __restrict__ h1, float* __restrict__ asrc, float* __restrict__ adst,
    int N, float* Wl, float (*xr)[64]) {
  int t = threadIdx.x;
  for (int i = t; i < 64 * 64; i += TPB) Wl[i] = W1[i];
  int w = t >> 6, lane = t & 63;
  int node = gb * 4 + w;
  if (node < N) xr[w][lane] = x[(size_t)node * 64 + lane];
  __syncthreads();
  if (node >= N) return;
  float acc = 0.f;
#pragma unroll
  for (int k = 0; k < 64; ++k) acc = fmaf(xr[w][k], Wl[k * 64 + lane], acc);
  h1[(size_t)node * 64 + lane] = __float2half(acc);
  float vs = acc * aS[lane];
  float vd = acc * aD[lane];
#pragma unroll
  for (int m = 16; m >= 1; m >>= 1) {
    vs += __shfl_xor(vs, m, 64);
    vd += __shfl_xor(vd, m, 64);
  }
  if ((lane & 31) == 0) {
    asrc[node * 2 + (lane >> 5)] = vs;
    adst[node * 2 + (lane >> 5)] = vd;
  }
}

// ---------- fat kernel 1: CSR histogram (blocks 0..B1) + gemm1 first half ----------
__global__ __launch_bounds__(TPB) void k_fat1(
    const void* __restrict__ ei, int E, int Etot,
    int* __restrict__ histA, int NB, int CH,
    const float* __restrict__ x, const float* __restrict__ W1,
    const float* __restrict__ aS, const float* __restrict__ aD,
    __half* __restrict__ h1, float* __restrict__ asrc, float* __restrict__ adst,
    int N) {
  __shared__ float Wl[64 * 64];
  __shared__ float xr[4][64];
  __shared__ int lh[MAXNB];
  __shared__ int sflag;
  if (blockIdx.x >= B1) {
    gemm1_body((int)blockIdx.x - B1, x, W1, aS, aD, h1, asrc, adst, N, Wl, xr);
    return;
  }
  int b = blockIdx.x, tid = threadIdx.x;
  for (int i = tid; i < NB; i += TPB) lh[i] = 0;
  if (tid < 64) {  // wave 0: sniff int32 vs int64 storage (ids < 2^31)
    const unsigned long long* p = (const unsigned long long*)ei;
    unsigned long long m = __ballot(tid < E && p[tid] > 0xFFFFFFFFULL);
    if (tid == 0) sflag = (m != 0ULL) ? 1 : 0;
  }
  __syncthreads();
  int f = sflag;
  int beg = b * CH, end = min(beg + CH, Etot);
  for (int e = beg + tid; e < end; e += TPB) {
    int d = (e < E) ? getIdx(ei, f, (long long)E + e) : e - E;
    atomicAdd(&lh[d / DPB], 1);
  }
  __syncthreads();
  for (int i = tid; i < NB; i += TPB) histA[b * NB + i] = lh[i];  // [block][bucket]
}

// ---------- fat kernel 2: CSR place (scan inlined) + gemm1 second half ----------
__global__ __launch_bounds__(TPB) void k_fat2(
    const void* __restrict__ ei, int E, int Etot,
    const int* __restrict__ histA, int* __restrict__ bucketBase,
    int2* __restrict__ pairs, int NB, int CH,
    const float* __restrict__ x, const float* __restrict__ W1,
    const float* __restrict__ aS, const float* __restrict__ aD,
    __half* __restrict__ h1, float* __restrict__ asrc, float* __restrict__ adst,
    int N, int gOff) {
  __shared__ float Wl[64 * 64];
  __shared__ float xr[4][64];
  __shared__ int cur[MAXNB];
  __shared__ int sh[TPB];
  __shared__ int sflag;
  if (blockIdx.x >= B1) {
    gemm1_body((int)blockIdx.x - B1 + gOff, x, W1, aS, aD, h1, asrc, adst, N, Wl, xr);
    return;
  }
  int b = blockIdx.x, tid = threadIdx.x;
  int before = 0, tot = 0;
  if (tid < NB) {
    for (int bb = 0; bb < B1; ++bb) {        // coalesced: histA[bb*NB + tid]
      int v = histA[bb * NB + tid];
      tot += v;
      if (bb < b) before += v;
    }
  }
  if (tid < 64) {
    const unsigned long long* p = (const unsigned long long*)ei;
    unsigned long long m = __ballot(tid < E && p[tid] > 0xFFFFFFFFULL);
    if (tid == 0) sflag = (m != 0ULL) ? 1 : 0;
  }
  sh[tid] = (tid < NB) ? tot : 0;
  __syncthreads();
  for (int off = 1; off < TPB; off <<= 1) {
    int v = (tid >= off) ? sh[tid - off] : 0;
    __syncthreads();
    sh[tid] += v;
    __syncthreads();
  }
  int excl = sh[tid] - ((tid < NB) ? tot : 0);
  if (tid < NB) cur[tid] = excl + before;
  if (b == 0 && tid < NB) bucketBase[tid] = excl;
  if (b == 0 && tid == NB - 1) bucketBase[NB] = sh[tid];  // total == Etot
  int f = sflag;
  __syncthreads();
  int beg = b * CH, end = min(beg + CH, Etot);
  for (int e = beg + tid; e < end; e += TPB) {
    int s, d;
    if (e < E) {
      s = getIdx(ei, f, e);
      d = getIdx(ei, f, (long long)E + e);
    } else {
      s = d = e - E;
    }
    int pos = atomicAdd(&cur[d / DPB], 1);
    pairs[pos] = make_int2(s, d);
  }
}

// ---------- CSR stage 3: per-bucket hist+scan -> rowptr, then place csr_src ----------
__global__ __launch_bounds__(DPB) void k_bucket(
    const int2* __restrict__ pairs, const int* __restrict__ bucketBase,
    int* __restrict__ rowptr, int* __restrict__ csr_src, int N, int Etot) {
  __shared__ int cnt[DPB];
  __shared__ int sc[DPB];
  int g = blockIdx.x, tid = threadIdx.x;
  int base = g * DPB;
  int nd = N - base; if (nd > DPB) nd = DPB;
  cnt[tid] = 0;
  __syncthreads();
  int beg = bucketBase[g], end = bucketBase[g + 1];
  for (int j = beg + tid; j < end; j += DPB)
    atomicAdd(&cnt[pairs[j].y & (DPB - 1)], 1);
  __syncthreads();
  sc[tid] = cnt[tid];
  __syncthreads();
  for (int off = 1; off < DPB; off <<= 1) {
    int v = (tid >= off) ? sc[tid - off] : 0;
    __syncthreads();
    sc[tid] += v;
    __syncthreads();
  }
  int excl = beg + sc[tid] - cnt[tid];
  if (tid < nd) rowptr[base + tid] = excl;
  if (g == 0 && tid == 0) rowptr[N] = Etot;
  __syncthreads();
  cnt[tid] = excl;  // becomes cursor
  __syncthreads();
  for (int j = beg + tid; j < end; j += DPB) {
    int2 p = pairs[j];
    int pos = atomicAdd(&cnt[p.y & (DPB - 1)], 1);
    csr_src[pos] = p.x;
  }
}

// ---------- fused layer-1 gather + layer-2 linear: half-wave per node ----------
__global__ __launch_bounds__(TPB) void k_gather1f(
    const int* __restrict__ rowptr, const int* __restrict__ csr_src,
    const float* __restrict__ as1, const float* __restrict__ ad1,
    const __half* __restrict__ h1, const float* __restrict__ b1,
    const float* __restrict__ W2, const float* __restrict__ aS2,
    const float* __restrict__ aD2,
    __half* __restrict__ h2, float* __restrict__ as2, float* __restrict__ ad2, int N) {
  __shared__ float W2s[64 * 32];
  __shared__ float aS2s[32], aD2s[32];
  __shared__ int   sSid[8][32];
  __shared__ float sWp[8][64];
  __shared__ float rowBuf[8][64];
  int t = threadIdx.x;
  for (int i = t; i < 64 * 32; i += TPB) W2s[i] = W2[i];
  if (t < 32) { aS2s[t] = aS2[t]; aD2s[t] = aD2[t]; }
  __syncthreads();

  int hw = t >> 5, lane32 = t & 31;
  int node = blockIdx.x * 8 + hw;
  if (node >= N) return;

  int e4 = lane32 >> 3, c8 = lane32 & 7;  // c8 owns halfs [c8*8, c8*8+8)
  int head = c8 >> 2;                     // head of those 8 feats
  float2 adv = *(const float2*)(ad1 + (size_t)node * 2);
  int beg = rowptr[node], end = rowptr[node + 1];
  float a0 = 0.f, a1 = 0.f, a2 = 0.f, a3 = 0.f;
  float a4 = 0.f, a5 = 0.f, a6 = 0.f, a7 = 0.f;
  float d0L = 0.f, d1L = 0.f;
  for (int chunk = beg; chunk < end; chunk += 32) {
    int m = end - chunk; if (m > 32) m = 32;
    int sid = 0; float w0 = 0.f, w1 = 0.f;   // zero-pad: wgt 0 contributes nothing
    if (lane32 < m) {                        // phase 1: up to 32 edges in parallel
      sid = csr_src[chunk + lane32];
      float2 av = *(const float2*)(as1 + (size_t)sid * 2);
      float v0 = av.x + adv.x, v1 = av.y + adv.y;
      v0 = v0 > 0.f ? v0 : NEG_SLOPE * v0;
      v1 = v1 > 0.f ? v1 : NEG_SLOPE * v1;
      w0 = __expf(v0); w1 = __expf(v1);
      d0L += w0; d1L += w1;
    }
    sSid[hw][lane32] = sid;                  // unconditional full staging
    *(float2*)&sWp[hw][lane32 * 2] = make_float2(w0, w1);
    // same-wave LDS handoff (lockstep, in-order LDS pipe)
    for (int j = 0; j < m; j += 8) {         // phase 2: 8 edges per iteration
      int j0 = j + e4, j1 = j0 + 4;
      int s0 = sSid[hw][j0], s1 = sSid[hw][j1];
      float q0 = sWp[hw][j0 * 2 + head], q1 = sWp[hw][j1 * 2 + head];
      float4 r0 = *(const float4*)(h1 + (size_t)s0 * 64 + c8 * 8);
      float4 r1 = *(const float4*)(h1 + (size_t)s1 * 64 + c8 * 8);
      const __half2* p0 = (const __half2*)&r0;
      const __half2* p1 = (const __half2*)&r1;
      float2 u;
      u = __half22float2(p0[0]); a0 = fmaf(q0, u.x, a0); a1 = fmaf(q0, u.y, a1);
      u = __half22float2(p0[1]); a2 = fmaf(q0, u.x, a2); a3 = fmaf(q0, u.y, a3);
      u = __half22float2(p0[2]); a4 = fmaf(q0, u.x, a4); a5 = fmaf(q0, u.y, a5);
      u = __half22float2(p0[3]); a6 = fmaf(q0, u.x, a6); a7 = fmaf(q0, u.y, a7);
      u = __half22float2(p1[0]); a0 = fmaf(q1, u.x, a0); a1 = fmaf(q1, u.y, a1);
      u = __half22float2(p1[1]); a2 = fmaf(q1, u.x, a2); a3 = fmaf(q1, u.y, a3);
      u = __half22float2(p1[2]); a4 = fmaf(q1, u.x, a4); a5 = fmaf(q1, u.y, a5);
      u = __half22float2(p1[3]); a6 = fmaf(q1, u.x, a6); a7 = fmaf(q1, u.y, a7);
    }
  }
  // combine the 4 edge-slot groups (xor 8,16 stays within the half-wave)
#pragma unroll
  for (int m2 = 8; m2 <= 16; m2 <<= 1) {
    a0 += __shfl_xor(a0, m2, 64); a1 += __shfl_xor(a1, m2, 64);
    a2 += __shfl_xor(a2, m2, 64); a3 += __shfl_xor(a3, m2, 64);
    a4 += __shfl_xor(a4, m2, 64); a5 += __shfl_xor(a5, m2, 64);
    a6 += __shfl_xor(a6, m2, 64); a7 += __shfl_xor(a7, m2, 64);
  }
#pragma unroll
  for (int m2 = 1; m2 <= 16; m2 <<= 1) {  // denominators over the half-wave
    d0L += __shfl_xor(d0L, m2, 64);
    d1L += __shfl_xor(d1L, m2, 64);
  }
  float inv = 1.f / ((head == 0 ? d0L : d1L) + 1e-16f);
  if (e4 == 0) {                          // lanes 0..7 of the half own the row
    float4 bb0 = *(const float4*)(b1 + c8 * 8);
    float4 bb1 = *(const float4*)(b1 + c8 * 8 + 4);
    float4 o0, o1;
    o0.x = fmaf(a0, inv, bb0.x); o0.y = fmaf(a1, inv, bb0.y);
    o0.z = fmaf(a2, inv, bb0.z); o0.w = fmaf(a3, inv, bb0.w);
    o1.x = fmaf(a4, inv, bb1.x); o1.y = fmaf(a5, inv, bb1.y);
    o1.z = fmaf(a6, inv, bb1.z); o1.w = fmaf(a7, inv, bb1.w);
    o0.x = o0.x > 0.f ? o0.x : 0.f; o0.y = o0.y > 0.f ? o0.y : 0.f;
    o0.z = o0.z > 0.f ? o0.z : 0.f; o0.w = o0.w > 0.f ? o0.w : 0.f;
    o1.x = o1.x > 0.f ? o1.x : 0.f; o1.y = o1.y > 0.f ? o1.y : 0.f;
    o1.z = o1.z > 0.f ? o1.z : 0.f; o1.w = o1.w > 0.f ? o1.w : 0.f;
    *(float4*)&rowBuf[hw][c8 * 8] = o0;
    *(float4*)&rowBuf[hw][c8 * 8 + 4] = o1;
  }
  // layer-2 dot: lane32 = output col; row broadcast + W2 from LDS (same-wave handoff)
  int c = lane32;
  float acc2 = 0.f;
#pragma unroll
  for (int k = 0; k < 64; ++k)
    acc2 = fmaf(rowBuf[hw][k], W2s[k * 32 + c], acc2);
  h2[(size_t)node * 32 + c] = __float2half(acc2);
  float vs = acc2 * aS2s[c];
  float vd = acc2 * aD2s[c];
#pragma unroll
  for (int m2 = 1; m2 <= 16; m2 <<= 1) {
    vs += __shfl_xor(vs, m2, 64);
    vd += __shfl_xor(vd, m2, 64);
  }
  if (lane32 == 0) {
    as2[node] = vs;
    ad2[node] = vd;
  }
}

// ---------- layer 2 gather: half-wave per node, 8 edge-slots, 2-deep unroll ----------
__global__ __launch_bounds__(TPB) void k_gather2(
    const int* __restrict__ rowptr, const int* __restrict__ csr_src,
    const float* __restrict__ as2, const float* __restrict__ ad2,
    const __half* __restrict__ h2, const float* __restrict__ b,
    float* __restrict__ out, int N) {
  __shared__ int   sS[8][32];
  __shared__ float sWv[8][32];
  int t = threadIdx.x;
  int hw = t >> 5, lane32 = t & 31;
  int wid = blockIdx.x * 8 + hw;
  if (wid >= N) return;
  int e8 = lane32 >> 2, c4 = lane32 & 3;   // c4 owns halfs [c4*8, c4*8+8)
  float ad = ad2[wid];
  int beg = rowptr[wid], end = rowptr[wid + 1];
  float a0 = 0.f, a1 = 0.f, a2 = 0.f, a3 = 0.f;
  float a4 = 0.f, a5 = 0.f, a6 = 0.f, a7 = 0.f;
  float dL = 0.f;
  for (int chunk = beg; chunk < end; chunk += 32) {
    int m = end - chunk; if (m > 32) m = 32;
    int sid = 0; float wv = 0.f;
    if (lane32 < m) {                      // phase 1
      sid = csr_src[chunk + lane32];
      float v = as2[sid] + ad;
      v = v > 0.f ? v : NEG_SLOPE * v;
      wv = __expf(v);
      dL += wv;
    }
    sS[hw][lane32] = sid;
    sWv[hw][lane32] = wv;
    for (int j = 0; j < m; j += 16) {      // phase 2: 16 edges per iteration
      int j0 = j + e8, j1 = j0 + 8;
      int s0 = sS[hw][j0], s1 = sS[hw][j1];
      float q0 = sWv[hw][j0], q1 = sWv[hw][j1];
      float4 r0 = *(const float4*)(h2 + (size_t)s0 * 32 + c4 * 8);
      float4 r1 = *(const float4*)(h2 + (size_t)s1 * 32 + c4 * 8);
      const __half2* p0 = (const __half2*)&r0;
      const __half2* p1 = (const __half2*)&r1;
      float2 u;
      u = __half22float2(p0[0]); a0 = fmaf(q0, u.x, a0); a1 = fmaf(q0, u.y, a1);
      u = __half22float2(p0[1]); a2 = fmaf(q0, u.x, a2); a3 = fmaf(q0, u.y, a3);
      u = __half22float2(p0[2]); a4 = fmaf(q0, u.x, a4); a5 = fmaf(q0, u.y, a5);
      u = __half22float2(p0[3]); a6 = fmaf(q0, u.x, a6); a7 = fmaf(q0, u.y, a7);
      u = __half22float2(p1[0]); a0 = fmaf(q1, u.x, a0); a1 = fmaf(q1, u.y, a1);
      u = __half22float2(p1[1]); a2 = fmaf(q1, u.x, a2); a3 = fmaf(q1, u.y, a3);
      u = __half22float2(p1[2]); a4 = fmaf(q1, u.x, a4); a5 = fmaf(q1, u.y, a5);
      u = __half22float2(p1[3]); a6 = fmaf(q1, u.x, a6); a7 = fmaf(q1, u.y, a7);
    }
  }
#pragma unroll
  for (int m2 = 4; m2 <= 16; m2 <<= 1) {   // combine the 8 edge-slot groups
    a0 += __shfl_xor(a0, m2, 64); a1 += __shfl_xor(a1, m2, 64);
    a2 += __shfl_xor(a2, m2, 64); a3 += __shfl_xor(a3, m2, 64);
    a4 += __shfl_xor(a4, m2, 64); a5 += __shfl_xor(a5, m2, 64);
    a6 += __shfl_xor(a6, m2, 64); a7 += __shfl_xor(a7, m2, 64);
  }
#pragma unroll
  for (int m2 = 1; m2 <= 16; m2 <<= 1) dL += __shfl_xor(dL, m2, 64);
  if (e8 == 0) {                           // lanes 0..3 of the half own the row
    float inv = 1.f / (dL + 1e-16f);
    float4 bv0 = *(const float4*)(b + c4 * 8);
    float4 bv1 = *(const float4*)(b + c4 * 8 + 4);
    float4 o0, o1;
    o0.x = fmaf(a0, inv, bv0.x); o0.y = fmaf(a1, inv, bv0.y);
    o0.z = fmaf(a2, inv, bv0.z); o0.w = fmaf(a3, inv, bv0.w);
    o1.x = fmaf(a4, inv, bv1.x); o1.y = fmaf(a5, inv, bv1.y);
    o1.z = fmaf(a6, inv, bv1.z); o1.w = fmaf(a7, inv, bv1.w);
    *(float4*)(out + (size_t)wid * 32 + c4 * 8) = o0;
    *(float4*)(out + (size_t)wid * 32 + c4 * 8 + 4) = o1;
  }
}

extern "C" void kernel_launch(void* const* d_in, const int* in_sizes, int n_in,
                              void* d_out, int out_size, void* d_ws, size_t ws_size,
                              hipStream_t stream) {
  const float* x   = (const float*)d_in[0];
  const void*  ei  = d_in[1];
  const float* W1  = (const float*)d_in[2];
  const float* aS1 = (const float*)d_in[3];
  const float* aD1 = (const float*)d_in[4];
  const float* b1  = (const float*)d_in[5];
  const float* W2  = (const float*)d_in[6];
  const float* aS2 = (const float*)d_in[7];
  const float* aD2 = (const float*)d_in[8];
  const float* b2  = (const float*)d_in[9];
  float* out = (float*)d_out;

  int N = in_sizes[0] / 64;
  int E = in_sizes[1] / 2;
  int Etot = E + N;
  int NB = (N + DPB - 1) / DPB;         // dst buckets
  int CH = (Etot + B1 - 1) / B1;        // edges per hist/place block
  int gAll = (N + 3) / 4;               // gemm1 blocks total
  int g1 = gAll / 2, g2 = gAll - g1;    // split across the two fat kernels

  float* W = (float*)d_ws;
  size_t o = 0;
  __half* h1 = (__half*)(W + o); o += (size_t)N * 32;   // N*64 halfs
  // pairs (int2, Etot) shares storage with h2 (N*32 halfs): disjoint lifetimes
  size_t regB = (size_t)(2 * (size_t)Etot > (size_t)N * 16 ? 2 * (size_t)Etot : (size_t)N * 16);
  int2* pairs = (int2*)(W + o);
  __half* h2  = (__half*)(W + o);
  o += regB;
  float* as1  = W + o; o += (size_t)N * 2;
  float* ad1  = W + o; o += (size_t)N * 2;
  float* as2  = W + o; o += (size_t)N;
  float* ad2  = W + o; o += (size_t)N;
  int* ip = (int*)(W + o);
  size_t io = 0;
  int* histA      = ip + io; io += (size_t)NB * B1;
  int* bucketBase = ip + io; io += NB + 1;
  int* rowptr     = ip + io; io += N + 1;
  int* csr_src    = ip + io; io += Etot;

  // CSR build overlapped with gemm1 (independent work rides along as extra blocks)
  k_fat1<<<B1 + g1, TPB, 0, stream>>>(ei, E, Etot, histA, NB, CH,
                                      x, W1, aS1, aD1, h1, as1, ad1, N);
  k_fat2<<<B1 + g2, TPB, 0, stream>>>(ei, E, Etot, histA, bucketBase, pairs, NB, CH,
                                      x, W1, aS1, aD1, h1, as1, ad1, N, g1);
  k_bucket<<<NB, DPB, 0, stream>>>(pairs, bucketBase, rowptr, csr_src, N, Etot);

  // fused layer-1 gather + layer-2 linear
  k_gather1f<<<(N + 7) / 8, TPB, 0, stream>>>(rowptr, csr_src, as1, ad1, h1, b1,
                                              W2, aS2, aD2, h2, as2, ad2, N);

  // layer 2 gather -> output
  k_gather2<<<(N + 7) / 8, TPB, 0, stream>>>(rowptr, csr_src, as2, ad2, h2, b2, out, N);
}